// Round 16
// baseline (156.865 us; speedup 1.0000x reference)
//
#include <hip/hip_runtime.h>
#include <hip/hip_fp16.h>
#include <math.h>

#define N_NODES 100000
#define N_EDGES 3200000
#define F_IN    128
#define NGRAPH  64

// ---- dst-binning: 512 buckets of BWIDTH nodes ----
#define NB      512
#define BWIDTH  196            // 512*196 = 100352 >= N; dstLocal < 256 -> fits <<17 pack
#define NPAD    100352
#define BIN_CAP 7200           // mean 6250, sigma ~79 -> +12 sigma
#define EPB     4096           // edges per bin_k block (512 thr x 8)
#define PWIN    2048           // degree-sort window (keeps batch locality)

typedef int   iv4 __attribute__((ext_vector_type(4)));
typedef float fv4 __attribute__((ext_vector_type(4)));
typedef float fv2 __attribute__((ext_vector_type(2)));

// Workspace layout (4-byte elements)
#define OFF_BINCUR 0                          // [512] int
#define OFF_GZ     512                        // [64] f32 pooled z per graph
#define OFF_BBASE  576                        // [512] int bucket edge bases
#define OFF_DIS    1088                       // [NPAD] f32
#define OFF_DEG    (1088 + NPAD)              // [NPAD] int  node in-degree
#define OFF_PERM   (1088 + NPAD * 2)          // [NPAD] int  degree-sorted order
#define OFF_ROWR   (1088 + NPAD * 3)          // [2*NPAD] int2 rowRange
#define OFF_COL    (1088 + NPAD * 5)          // [E] int CSR col
#define OFF_BINNED (OFF_COL + N_EDGES)        // [NB*BIN_CAP] int (dead after sort_k)
#define OFF_HINH   OFF_BINNED                 // [NPAD*8 words] fp16 layer-1 hin'
#define OFF_HINH2  (OFF_BINNED + NPAD * 8)    // [NPAD*8 words] fp16 layer-2 hin'

// ---- zero bin cursors + per-graph z (binCur[512] and gz[64] contiguous) ----
__global__ void zero_k(int* __restrict__ p) {
    p[threadIdx.x] = 0;
}

// ---- pass A: bin edges by dst range; packed (dstLocal<<17 | src) ----
__global__ void __launch_bounds__(512)
bin_k(const int* __restrict__ ei, int* __restrict__ binCursor,
      int* __restrict__ binned) {
    __shared__ int cntL[NB], cnt2[NB], gbase[NB];
    int tid = threadIdx.x;
    cntL[tid] = 0; cnt2[tid] = 0;
    __syncthreads();
    int myBase = blockIdx.x * EPB + tid * 8;
    bool act = (myBase < N_EDGES);   // tail multiple of 8 -> all-or-none per thread
    int s[8], d[8];
    if (act) {
        const iv4* sp = (const iv4*)(ei + myBase);
        const iv4* dp = (const iv4*)(ei + N_EDGES + myBase);
        iv4 a = __builtin_nontemporal_load(sp);
        iv4 b2 = __builtin_nontemporal_load(sp + 1);
        iv4 c = __builtin_nontemporal_load(dp);
        iv4 e = __builtin_nontemporal_load(dp + 1);
        s[0]=a.x; s[1]=a.y; s[2]=a.z; s[3]=a.w; s[4]=b2.x; s[5]=b2.y; s[6]=b2.z; s[7]=b2.w;
        d[0]=c.x; d[1]=c.y; d[2]=c.z; d[3]=c.w; d[4]=e.x; d[5]=e.y; d[6]=e.z; d[7]=e.w;
#pragma unroll
        for (int k = 0; k < 8; ++k)
            atomicAdd(&cntL[(unsigned)d[k] / BWIDTH], 1);
    }
    __syncthreads();
    gbase[tid] = atomicAdd(&binCursor[tid], cntL[tid]);
    __syncthreads();
    if (act) {
#pragma unroll
        for (int k = 0; k < 8; ++k) {
            int b = (unsigned)d[k] / BWIDTH;
            int off = atomicAdd(&cnt2[b], 1);
            binned[(size_t)b * BIN_CAP + gbase[b] + off] = ((d[k] - b * BWIDTH) << 17) | s[k];
        }
    }
}

// ---- exclusive scan of 512 bucket sizes -> dense edge bases (one block) ----
__global__ void __launch_bounds__(512)
scanB_k(const int* __restrict__ binCur, int* __restrict__ bucketBase) {
    __shared__ int wsum[8];
    int tid = threadIdx.x;
    int v = binCur[tid];
    int lane = tid & 63, wid = tid >> 6;
    int sc = v;
#pragma unroll
    for (int d = 1; d < 64; d <<= 1) {
        int o = __shfl_up(sc, d);
        if (lane >= d) sc += o;
    }
    if (lane == 63) wsum[wid] = sc;
    __syncthreads();
    int woff = 0;
    for (int w = 0; w < wid; ++w) woff += wsum[w];
    bucketBase[tid] = woff + sc - v;
}

// ---- per-bucket counting sort: histogram -> dis/deg + rowRange, scatter col ----
__global__ void __launch_bounds__(512)
sort_k(const int* __restrict__ binCursor, const int* __restrict__ bucketBase,
       const int* __restrict__ binned, float* __restrict__ dis,
       int* __restrict__ deg, int2* __restrict__ rowRange, int* __restrict__ col) {
    __shared__ int cnt[BWIDTH];
    __shared__ int rowLoc[BWIDTH + 1];
    __shared__ int cur[BWIDTH];
    __shared__ int wsum[8];
    int b = blockIdx.x, tid = threadIdx.x;
    if (tid < BWIDTH) cnt[tid] = 0;
    __syncthreads();
    int n = binCursor[b];
    const int* bb = binned + (size_t)b * BIN_CAP;
    for (int i = tid; i < n; i += 512)
        atomicAdd(&cnt[bb[i] >> 17], 1);
    __syncthreads();
    int base = b * BWIDTH;
    int bw = min(BWIDTH, N_NODES - base);
    if (tid < bw) {
        dis[base + tid] = rsqrtf((float)cnt[tid] + 1.0f);
        deg[base + tid] = cnt[tid];
    }
    int a = (tid < BWIDTH) ? cnt[tid] : 0;
    int lane = tid & 63, wid = tid >> 6;
    int sc = a;
#pragma unroll
    for (int d = 1; d < 64; d <<= 1) {
        int o = __shfl_up(sc, d);
        if (lane >= d) sc += o;
    }
    if (lane == 63) wsum[wid] = sc;
    __syncthreads();
    int woff = 0;
    for (int w = 0; w < wid; ++w) woff += wsum[w];
    if (tid < BWIDTH) {
        int excl = woff + sc - a;
        rowLoc[tid] = excl;
        cur[tid] = excl;
    }
    if (tid == 0) rowLoc[BWIDTH] = n;
    __syncthreads();
    int eb = bucketBase[b];
    if (tid < bw) {
        int2 rr; rr.x = eb + rowLoc[tid]; rr.y = eb + rowLoc[tid + 1];
        rowRange[base + tid] = rr;
    }
    for (int i = tid; i < n; i += 512) {
        int p = bb[i];
        int pos = atomicAdd(&cur[p >> 17], 1);
        col[eb + pos] = p & 0x1FFFF;
    }
}

// ---- windowed degree sort: counting-sort nodes by degree within 2048-node
// windows. Waves then process equal-degree nodes -> max~=mean (was max-of-8
// Poisson(32) ~= 1.4x mean). Window-local => batch clustering preserved for
// prop2's LDS pool. All-LDS, no global atomics.
__global__ void __launch_bounds__(512)
permW_k(const int* __restrict__ deg, int* __restrict__ perm) {
    __shared__ int hist[128];
    int w0 = blockIdx.x * PWIN;
    int wn = min(PWIN, N_NODES - w0);
    int tid = threadIdx.x;
    if (tid < 128) hist[tid] = 0;
    __syncthreads();
    int mybin[4];
#pragma unroll
    for (int k = 0; k < 4; ++k) {
        int i = tid * 4 + k;
        mybin[k] = -1;
        if (i < wn) {
            int d = min(deg[w0 + i], 127);
            mybin[k] = d;
            atomicAdd(&hist[d], 1);
        }
    }
    __syncthreads();
    if (tid == 0) {
        int acc = 0;
#pragma unroll
        for (int bN = 0; bN < 128; ++bN) { int c = hist[bN]; hist[bN] = acc; acc += c; }
    }
    __syncthreads();
#pragma unroll
    for (int k = 0; k < 4; ++k) {
        int i = tid * 4 + k;
        if (i < wn) {
            int pos = atomicAdd(&hist[mybin[k]], 1);
            perm[w0 + pos] = w0 + i;
        }
    }
}

// ---- hin' = fp16( dis[i] * (x @ W1) ), packed 16 halfs/node (32B) ----
__global__ void transform1_k(const float* __restrict__ x, const float* __restrict__ W,
                             const float* __restrict__ dis, __half* __restrict__ outh) {
    int i = blockIdx.x * blockDim.x + threadIdx.x;
    if (i >= N_NODES) return;
    const fv4* xr = (const fv4*)(x + (size_t)i * F_IN);
    float acc[16];
#pragma unroll
    for (int j = 0; j < 16; ++j) acc[j] = 0.f;
#pragma unroll 4
    for (int k4 = 0; k4 < F_IN / 4; ++k4) {
        fv4 xv = xr[k4];
#pragma unroll
        for (int kk = 0; kk < 4; ++kk) {
            int k = k4 * 4 + kk;
            float xk = xv[kk];
#pragma unroll
            for (int j = 0; j < 16; ++j)
                acc[j] = fmaf(xk, W[k * 16 + j], acc[j]);
        }
    }
    float di = dis[i];
    __half2 t[8];
#pragma unroll
    for (int q = 0; q < 8; ++q)
        t[q] = __floats2half2_rn(di * acc[2 * q], di * acc[2 * q + 1]);
    iv4* o = (iv4*)(outh + (size_t)i * 16);
    o[0] = *(iv4*)&t[0];
    o[1] = *(iv4*)&t[4];
}

// gather-accumulate: 8-lane group, __half2/lane, tiers 8/4/1; coalesced
// shfl-broadcast col loads (round-15: +3us on prop2).
__device__ __forceinline__ void gather_row(const __half2* __restrict__ hh,
                                           const int* __restrict__ col,
                                           int e0, int e1, int j,
                                           float& outx, float& outy) {
    float ax0 = 0.f, ay0 = 0.f, ax1 = 0.f, ay1 = 0.f;
    float ax2 = 0.f, ay2 = 0.f, ax3 = 0.f, ay3 = 0.f;
    float bx0 = 0.f, by0 = 0.f, bx1 = 0.f, by1 = 0.f;
    float bx2 = 0.f, by2 = 0.f, bx3 = 0.f, by3 = 0.f;
    int e = e0;
    for (; e + 8 <= e1; e += 8) {
        int myc = col[e + j];          // coalesced: 8 lanes -> one 32B line
        int s0 = __shfl(myc, 0, 8);
        int s1 = __shfl(myc, 1, 8);
        int s2 = __shfl(myc, 2, 8);
        int s3 = __shfl(myc, 3, 8);
        int s4 = __shfl(myc, 4, 8);
        int s5 = __shfl(myc, 5, 8);
        int s6 = __shfl(myc, 6, 8);
        int s7 = __shfl(myc, 7, 8);
        float2 f0 = __half22float2(hh[s0 * 8 + j]);
        float2 f1 = __half22float2(hh[s1 * 8 + j]);
        float2 f2 = __half22float2(hh[s2 * 8 + j]);
        float2 f3 = __half22float2(hh[s3 * 8 + j]);
        float2 f4 = __half22float2(hh[s4 * 8 + j]);
        float2 f5 = __half22float2(hh[s5 * 8 + j]);
        float2 f6 = __half22float2(hh[s6 * 8 + j]);
        float2 f7 = __half22float2(hh[s7 * 8 + j]);
        ax0 += f0.x; ay0 += f0.y;
        ax1 += f1.x; ay1 += f1.y;
        ax2 += f2.x; ay2 += f2.y;
        ax3 += f3.x; ay3 += f3.y;
        bx0 += f4.x; by0 += f4.y;
        bx1 += f5.x; by1 += f5.y;
        bx2 += f6.x; by2 += f6.y;
        bx3 += f7.x; by3 += f7.y;
    }
    if (e + 4 <= e1) {
        int myc = col[e + (j & 3)];    // lanes 4-7 duplicate lanes 0-3: 16B txn
        int s0 = __shfl(myc, 0, 8);
        int s1 = __shfl(myc, 1, 8);
        int s2 = __shfl(myc, 2, 8);
        int s3 = __shfl(myc, 3, 8);
        float2 f0 = __half22float2(hh[s0 * 8 + j]);
        float2 f1 = __half22float2(hh[s1 * 8 + j]);
        float2 f2 = __half22float2(hh[s2 * 8 + j]);
        float2 f3 = __half22float2(hh[s3 * 8 + j]);
        ax0 += f0.x; ay0 += f0.y;
        ax1 += f1.x; ay1 += f1.y;
        ax2 += f2.x; ay2 += f2.y;
        ax3 += f3.x; ay3 += f3.y;
        e += 4;
    }
    for (; e < e1; ++e) {
        float2 f = __half22float2(hh[col[e] * 8 + j]);
        ax0 += f.x; ay0 += f.y;
    }
    outx = ((ax0 + ax1) + (ax2 + ax3)) + ((bx0 + bx1) + (bx2 + bx3));
    outy = ((ay0 + ay1) + (ay2 + ay3)) + ((by0 + by1) + (by2 + by3));
}

// ---- prop layer 1 + FUSED transform2 (h1 never hits memory) ----
__global__ void prop1_k(const __half* __restrict__ hinh, const float* __restrict__ dis,
                        const int2* __restrict__ rowRange, const int* __restrict__ col,
                        const int* __restrict__ perm,
                        const float* __restrict__ b1, const float* __restrict__ W2,
                        __half* __restrict__ outh2) {
    int gid = blockIdx.x * blockDim.x + threadIdx.x;
    int grp = gid >> 3;
    int j = gid & 7;
    if (grp >= N_NODES) return;
    int node = perm[grp];
    int2 rr = rowRange[node];
    const __half2* hh = (const __half2*)hinh;
    float sx, sy;
    gather_row(hh, col, rr.x, rr.y, j, sx, sy);
    float2 self = __half22float2(hh[node * 8 + j]);
    float di = dis[node];
    fv2 bj = ((const fv2*)b1)[j];
    float hx = fmaxf(fmaf(di, sx + self.x, bj.x), 0.f);
    float hy = fmaxf(fmaf(di, sy + self.y, bj.y), 0.f);
    // regroup the node's 16 h1 features across the 8-lane group
    float h1[16];
#pragma unroll
    for (int k = 0; k < 8; ++k) {
        h1[2 * k]     = __shfl(hx, k, 8);
        h1[2 * k + 1] = __shfl(hy, k, 8);
    }
    const fv2* w2 = (const fv2*)W2;
    float o0 = 0.f, o1 = 0.f;
#pragma unroll
    for (int m = 0; m < 16; ++m) {
        fv2 wv = w2[m * 8 + j];
        o0 = fmaf(h1[m], wv.x, o0);
        o1 = fmaf(h1[m], wv.y, o1);
    }
    ((__half2*)outh2)[node * 8 + j] = __floats2half2_rn(di * o0, di * o1);
}

// ---- prop layer 2 + FUSED pool (256-thr blocks, round-13 proven) ----
__global__ void __launch_bounds__(256)
prop2_k(const __half* __restrict__ hinh2, const float* __restrict__ dis,
        const int2* __restrict__ rowRange, const int* __restrict__ col,
        const int* __restrict__ perm,
        const float* __restrict__ b2, const int* __restrict__ batch,
        const float* __restrict__ fcw, float* __restrict__ gz) {
    __shared__ float ldsz[NGRAPH];
    int tid = threadIdx.x;
    if (tid < NGRAPH) ldsz[tid] = 0.f;
    __syncthreads();
    int gid = blockIdx.x * 256 + tid;
    int grp = gid >> 3;
    int j = gid & 7;
    int node = perm[grp];
    int2 rr = rowRange[node];
    const __half2* hh = (const __half2*)hinh2;
    float sx, sy;
    gather_row(hh, col, rr.x, rr.y, j, sx, sy);
    float2 self = __half22float2(hh[node * 8 + j]);
    float di = dis[node];
    fv2 bj = ((const fv2*)b2)[j];
    float hx = fmaxf(fmaf(di, sx + self.x, bj.x), 0.f);
    float hy = fmaxf(fmaf(di, sy + self.y, bj.y), 0.f);
    fv2 fw = ((const fv2*)fcw)[j];
    float s = hx * fw.x + hy * fw.y;
#pragma unroll
    for (int off = 4; off; off >>= 1) s += __shfl_xor(s, off, 8);
    if (j == 0) atomicAdd(&ldsz[batch[node]], s);
    __syncthreads();
    if (tid < NGRAPH) {
        float v = ldsz[tid];
        if (v != 0.f) atomicAdd(&gz[tid], v);
    }
}

// ---- final: out[g] = sigmoid(gz[g] + fcb) ----
__global__ void sig_k(const float* __restrict__ gz, const float* __restrict__ fcb,
                      float* __restrict__ out) {
    int g = threadIdx.x;
    out[g] = 1.0f / (1.0f + expf(-(gz[g] + fcb[0])));
}

extern "C" void kernel_launch(void* const* d_in, const int* in_sizes, int n_in,
                              void* d_out, int out_size, void* d_ws, size_t ws_size,
                              hipStream_t stream) {
    const float* x    = (const float*)d_in[0];
    const int*   ei   = (const int*)d_in[1];
    const int*   batch= (const int*)d_in[2];
    const float* W1   = (const float*)d_in[3];
    const float* b1   = (const float*)d_in[4];
    const float* W2   = (const float*)d_in[5];
    const float* b2   = (const float*)d_in[6];
    const float* fcw  = (const float*)d_in[7];
    const float* fcb  = (const float*)d_in[8];
    float* out = (float*)d_out;

    float* ws = (float*)d_ws;
    int*    binCur   = (int*)(ws + OFF_BINCUR);
    float*  gz       = ws + OFF_GZ;
    int*    bucketBase = (int*)(ws + OFF_BBASE);
    float*  dis      = ws + OFF_DIS;
    int*    deg      = (int*)(ws + OFF_DEG);
    int*    perm     = (int*)(ws + OFF_PERM);
    int2*   rowRange = (int2*)(ws + OFF_ROWR);
    int*    col      = (int*)(ws + OFF_COL);
    int*    binned   = (int*)(ws + OFF_BINNED);
    __half* hinH     = (__half*)(ws + OFF_HINH);    // aliases binned (dead after sort_k)
    __half* hinH2    = (__half*)(ws + OFF_HINH2);   // aliases binned tail

    const int B = 256;
    int gN   = (N_NODES + B - 1) / B;            // 391
    int gNP  = (N_NODES * 8 + B - 1) / B;        // 3125 (exact)
    int gBin = (N_EDGES + EPB - 1) / EPB;        // 782
    int gPW  = (N_NODES + PWIN - 1) / PWIN;      // 49

    zero_k<<<1, 576, 0, stream>>>(binCur);       // binCur[512] + gz[64]
    bin_k<<<gBin, 512, 0, stream>>>(ei, binCur, binned);
    scanB_k<<<1, 512, 0, stream>>>(binCur, bucketBase);
    sort_k<<<NB, 512, 0, stream>>>(binCur, bucketBase, binned, dis, deg, rowRange, col);
    permW_k<<<gPW, 512, 0, stream>>>(deg, perm);

    transform1_k<<<gN, B, 0, stream>>>(x, W1, dis, hinH);
    prop1_k<<<gNP, B, 0, stream>>>(hinH, dis, rowRange, col, perm, b1, W2, hinH2);
    prop2_k<<<gNP, B, 0, stream>>>(hinH2, dis, rowRange, col, perm, b2, batch, fcw, gz);
    sig_k<<<1, NGRAPH, 0, stream>>>(gz, fcb, out);
}

// Round 17
// 147.904 us; speedup vs baseline: 1.0606x; 1.0606x over previous
//
#include <hip/hip_runtime.h>
#include <hip/hip_fp16.h>
#include <math.h>

#define N_NODES 100000
#define N_EDGES 3200000
#define F_IN    128
#define NGRAPH  64

// ---- dst-binning: 512 buckets of BWIDTH nodes ----
#define NB      512
#define BWIDTH  196            // 512*196 = 100352 >= N; dstLocal < 256 -> fits <<17 pack
#define NPAD    100352
#define BIN_CAP 7200           // mean 6250, sigma ~79 -> +12 sigma
#define EPB     4096           // edges per bin_k block (512 thr x 8)

typedef int   iv4 __attribute__((ext_vector_type(4)));
typedef float fv4 __attribute__((ext_vector_type(4)));
typedef float fv2 __attribute__((ext_vector_type(2)));

// Workspace layout (4-byte elements)
#define OFF_BINCUR 0                          // [512] int
#define OFF_GZ     512                        // [64] f32 pooled z per graph
#define OFF_BBASE  576                        // [512] int bucket edge bases
#define OFF_DIS    1088                       // [NPAD] f32
#define OFF_ROWR   (1088 + NPAD)              // [2*NPAD] int2 rowRange
#define OFF_COL    (1088 + NPAD * 3)          // [E] int CSR col
#define OFF_BINNED (OFF_COL + N_EDGES)        // [NB*BIN_CAP] int (dead after sort_k)
#define OFF_HINH   OFF_BINNED                 // [NPAD*8 words] fp16 layer-1 hin'
#define OFF_HINH2  (OFF_BINNED + NPAD * 8)    // [NPAD*8 words] fp16 layer-2 hin'

// ---- zero bin cursors + per-graph z (binCur[512] and gz[64] contiguous) ----
__global__ void zero_k(int* __restrict__ p) {
    p[threadIdx.x] = 0;
}

// ---- pass A: bin edges by dst range; packed (dstLocal<<17 | src) ----
__global__ void __launch_bounds__(512)
bin_k(const int* __restrict__ ei, int* __restrict__ binCursor,
      int* __restrict__ binned) {
    __shared__ int cntL[NB], cnt2[NB], gbase[NB];
    int tid = threadIdx.x;
    cntL[tid] = 0; cnt2[tid] = 0;
    __syncthreads();
    int myBase = blockIdx.x * EPB + tid * 8;
    bool act = (myBase < N_EDGES);   // tail multiple of 8 -> all-or-none per thread
    int s[8], d[8];
    if (act) {
        const iv4* sp = (const iv4*)(ei + myBase);
        const iv4* dp = (const iv4*)(ei + N_EDGES + myBase);
        iv4 a = __builtin_nontemporal_load(sp);
        iv4 b2 = __builtin_nontemporal_load(sp + 1);
        iv4 c = __builtin_nontemporal_load(dp);
        iv4 e = __builtin_nontemporal_load(dp + 1);
        s[0]=a.x; s[1]=a.y; s[2]=a.z; s[3]=a.w; s[4]=b2.x; s[5]=b2.y; s[6]=b2.z; s[7]=b2.w;
        d[0]=c.x; d[1]=c.y; d[2]=c.z; d[3]=c.w; d[4]=e.x; d[5]=e.y; d[6]=e.z; d[7]=e.w;
#pragma unroll
        for (int k = 0; k < 8; ++k)
            atomicAdd(&cntL[(unsigned)d[k] / BWIDTH], 1);
    }
    __syncthreads();
    gbase[tid] = atomicAdd(&binCursor[tid], cntL[tid]);
    __syncthreads();
    if (act) {
#pragma unroll
        for (int k = 0; k < 8; ++k) {
            int b = (unsigned)d[k] / BWIDTH;
            int off = atomicAdd(&cnt2[b], 1);
            binned[(size_t)b * BIN_CAP + gbase[b] + off] = ((d[k] - b * BWIDTH) << 17) | s[k];
        }
    }
}

// ---- exclusive scan of 512 bucket sizes -> dense edge bases (one block) ----
__global__ void __launch_bounds__(512)
scanB_k(const int* __restrict__ binCur, int* __restrict__ bucketBase) {
    __shared__ int wsum[8];
    int tid = threadIdx.x;
    int v = binCur[tid];
    int lane = tid & 63, wid = tid >> 6;
    int sc = v;
#pragma unroll
    for (int d = 1; d < 64; d <<= 1) {
        int o = __shfl_up(sc, d);
        if (lane >= d) sc += o;
    }
    if (lane == 63) wsum[wid] = sc;
    __syncthreads();
    int woff = 0;
    for (int w = 0; w < wid; ++w) woff += wsum[w];
    bucketBase[tid] = woff + sc - v;
}

// ---- per-bucket counting sort: histogram -> dis + rowRange, scatter -> col ----
__global__ void __launch_bounds__(512)
sort_k(const int* __restrict__ binCursor, const int* __restrict__ bucketBase,
       const int* __restrict__ binned, float* __restrict__ dis,
       int2* __restrict__ rowRange, int* __restrict__ col) {
    __shared__ int cnt[BWIDTH];
    __shared__ int rowLoc[BWIDTH + 1];
    __shared__ int cur[BWIDTH];
    __shared__ int wsum[8];
    int b = blockIdx.x, tid = threadIdx.x;
    if (tid < BWIDTH) cnt[tid] = 0;
    __syncthreads();
    int n = binCursor[b];
    const int* bb = binned + (size_t)b * BIN_CAP;
    for (int i = tid; i < n; i += 512)
        atomicAdd(&cnt[bb[i] >> 17], 1);
    __syncthreads();
    int base = b * BWIDTH;
    int bw = min(BWIDTH, N_NODES - base);
    if (tid < bw)
        dis[base + tid] = rsqrtf((float)cnt[tid] + 1.0f);
    int a = (tid < BWIDTH) ? cnt[tid] : 0;
    int lane = tid & 63, wid = tid >> 6;
    int sc = a;
#pragma unroll
    for (int d = 1; d < 64; d <<= 1) {
        int o = __shfl_up(sc, d);
        if (lane >= d) sc += o;
    }
    if (lane == 63) wsum[wid] = sc;
    __syncthreads();
    int woff = 0;
    for (int w = 0; w < wid; ++w) woff += wsum[w];
    if (tid < BWIDTH) {
        int excl = woff + sc - a;
        rowLoc[tid] = excl;
        cur[tid] = excl;
    }
    if (tid == 0) rowLoc[BWIDTH] = n;
    __syncthreads();
    int eb = bucketBase[b];
    if (tid < bw) {
        int2 rr; rr.x = eb + rowLoc[tid]; rr.y = eb + rowLoc[tid + 1];
        rowRange[base + tid] = rr;
    }
    for (int i = tid; i < n; i += 512) {
        int p = bb[i];
        int pos = atomicAdd(&cur[p >> 17], 1);
        col[eb + pos] = p & 0x1FFFF;
    }
}

// ---- hin' = fp16( dis[i] * (x @ W1) ), packed 16 halfs/node (32B) ----
__global__ void transform1_k(const float* __restrict__ x, const float* __restrict__ W,
                             const float* __restrict__ dis, __half* __restrict__ outh) {
    int i = blockIdx.x * blockDim.x + threadIdx.x;
    if (i >= N_NODES) return;
    const fv4* xr = (const fv4*)(x + (size_t)i * F_IN);
    float acc[16];
#pragma unroll
    for (int j = 0; j < 16; ++j) acc[j] = 0.f;
#pragma unroll 4
    for (int k4 = 0; k4 < F_IN / 4; ++k4) {
        fv4 xv = xr[k4];
#pragma unroll
        for (int kk = 0; kk < 4; ++kk) {
            int k = k4 * 4 + kk;
            float xk = xv[kk];
#pragma unroll
            for (int j = 0; j < 16; ++j)
                acc[j] = fmaf(xk, W[k * 16 + j], acc[j]);
        }
    }
    float di = dis[i];
    __half2 t[8];
#pragma unroll
    for (int q = 0; q < 8; ++q)
        t[q] = __floats2half2_rn(di * acc[2 * q], di * acc[2 * q + 1]);
    iv4* o = (iv4*)(outh + (size_t)i * 16);
    o[0] = *(iv4*)&t[0];
    o[1] = *(iv4*)&t[4];
}

// gather-accumulate: 8-lane group, __half2/lane, tiers 8/4/1; coalesced
// shfl-broadcast col loads (round-15: +3us on prop2). Node order is IDENTITY:
// round-16 proved degree-permuted order costs more (col stream locality,
// FETCH 25.5->46.7 MB) than wave balance saves.
__device__ __forceinline__ void gather_row(const __half2* __restrict__ hh,
                                           const int* __restrict__ col,
                                           int e0, int e1, int j,
                                           float& outx, float& outy) {
    float ax0 = 0.f, ay0 = 0.f, ax1 = 0.f, ay1 = 0.f;
    float ax2 = 0.f, ay2 = 0.f, ax3 = 0.f, ay3 = 0.f;
    float bx0 = 0.f, by0 = 0.f, bx1 = 0.f, by1 = 0.f;
    float bx2 = 0.f, by2 = 0.f, bx3 = 0.f, by3 = 0.f;
    int e = e0;
    for (; e + 8 <= e1; e += 8) {
        int myc = col[e + j];          // coalesced: 8 lanes -> one 32B line
        int s0 = __shfl(myc, 0, 8);
        int s1 = __shfl(myc, 1, 8);
        int s2 = __shfl(myc, 2, 8);
        int s3 = __shfl(myc, 3, 8);
        int s4 = __shfl(myc, 4, 8);
        int s5 = __shfl(myc, 5, 8);
        int s6 = __shfl(myc, 6, 8);
        int s7 = __shfl(myc, 7, 8);
        float2 f0 = __half22float2(hh[s0 * 8 + j]);
        float2 f1 = __half22float2(hh[s1 * 8 + j]);
        float2 f2 = __half22float2(hh[s2 * 8 + j]);
        float2 f3 = __half22float2(hh[s3 * 8 + j]);
        float2 f4 = __half22float2(hh[s4 * 8 + j]);
        float2 f5 = __half22float2(hh[s5 * 8 + j]);
        float2 f6 = __half22float2(hh[s6 * 8 + j]);
        float2 f7 = __half22float2(hh[s7 * 8 + j]);
        ax0 += f0.x; ay0 += f0.y;
        ax1 += f1.x; ay1 += f1.y;
        ax2 += f2.x; ay2 += f2.y;
        ax3 += f3.x; ay3 += f3.y;
        bx0 += f4.x; by0 += f4.y;
        bx1 += f5.x; by1 += f5.y;
        bx2 += f6.x; by2 += f6.y;
        bx3 += f7.x; by3 += f7.y;
    }
    if (e + 4 <= e1) {
        int myc = col[e + (j & 3)];    // lanes 4-7 duplicate lanes 0-3: 16B txn
        int s0 = __shfl(myc, 0, 8);
        int s1 = __shfl(myc, 1, 8);
        int s2 = __shfl(myc, 2, 8);
        int s3 = __shfl(myc, 3, 8);
        float2 f0 = __half22float2(hh[s0 * 8 + j]);
        float2 f1 = __half22float2(hh[s1 * 8 + j]);
        float2 f2 = __half22float2(hh[s2 * 8 + j]);
        float2 f3 = __half22float2(hh[s3 * 8 + j]);
        ax0 += f0.x; ay0 += f0.y;
        ax1 += f1.x; ay1 += f1.y;
        ax2 += f2.x; ay2 += f2.y;
        ax3 += f3.x; ay3 += f3.y;
        e += 4;
    }
    for (; e < e1; ++e) {
        float2 f = __half22float2(hh[col[e] * 8 + j]);
        ax0 += f.x; ay0 += f.y;
    }
    outx = ((ax0 + ax1) + (ax2 + ax3)) + ((bx0 + bx1) + (bx2 + bx3));
    outy = ((ay0 + ay1) + (ay2 + ay3)) + ((by0 + by1) + (by2 + by3));
}

// ---- prop layer 1 + FUSED transform2 (h1 never hits memory) ----
__global__ void prop1_k(const __half* __restrict__ hinh, const float* __restrict__ dis,
                        const int2* __restrict__ rowRange, const int* __restrict__ col,
                        const float* __restrict__ b1, const float* __restrict__ W2,
                        __half* __restrict__ outh2) {
    int gid = blockIdx.x * blockDim.x + threadIdx.x;
    int node = gid >> 3;
    int j = gid & 7;
    if (node >= N_NODES) return;
    int2 rr = rowRange[node];
    const __half2* hh = (const __half2*)hinh;
    float sx, sy;
    gather_row(hh, col, rr.x, rr.y, j, sx, sy);
    float2 self = __half22float2(hh[node * 8 + j]);
    float di = dis[node];
    fv2 bj = ((const fv2*)b1)[j];
    float hx = fmaxf(fmaf(di, sx + self.x, bj.x), 0.f);
    float hy = fmaxf(fmaf(di, sy + self.y, bj.y), 0.f);
    // regroup the node's 16 h1 features across the 8-lane group
    float h1[16];
#pragma unroll
    for (int k = 0; k < 8; ++k) {
        h1[2 * k]     = __shfl(hx, k, 8);
        h1[2 * k + 1] = __shfl(hy, k, 8);
    }
    const fv2* w2 = (const fv2*)W2;
    float o0 = 0.f, o1 = 0.f;
#pragma unroll
    for (int m = 0; m < 16; ++m) {
        fv2 wv = w2[m * 8 + j];
        o0 = fmaf(h1[m], wv.x, o0);
        o1 = fmaf(h1[m], wv.y, o1);
    }
    ((__half2*)outh2)[node * 8 + j] = __floats2half2_rn(di * o0, di * o1);
}

// ---- prop layer 2 + FUSED pool (256-thr blocks, round-13 proven) ----
__global__ void __launch_bounds__(256)
prop2_k(const __half* __restrict__ hinh2, const float* __restrict__ dis,
        const int2* __restrict__ rowRange, const int* __restrict__ col,
        const float* __restrict__ b2, const int* __restrict__ batch,
        const float* __restrict__ fcw, float* __restrict__ gz) {
    __shared__ float ldsz[NGRAPH];
    int tid = threadIdx.x;
    if (tid < NGRAPH) ldsz[tid] = 0.f;
    __syncthreads();
    int gid = blockIdx.x * 256 + tid;
    int node = gid >> 3;
    int j = gid & 7;
    int2 rr = rowRange[node];
    const __half2* hh = (const __half2*)hinh2;
    float sx, sy;
    gather_row(hh, col, rr.x, rr.y, j, sx, sy);
    float2 self = __half22float2(hh[node * 8 + j]);
    float di = dis[node];
    fv2 bj = ((const fv2*)b2)[j];
    float hx = fmaxf(fmaf(di, sx + self.x, bj.x), 0.f);
    float hy = fmaxf(fmaf(di, sy + self.y, bj.y), 0.f);
    fv2 fw = ((const fv2*)fcw)[j];
    float s = hx * fw.x + hy * fw.y;
#pragma unroll
    for (int off = 4; off; off >>= 1) s += __shfl_xor(s, off, 8);
    if (j == 0) atomicAdd(&ldsz[batch[node]], s);
    __syncthreads();
    if (tid < NGRAPH) {
        float v = ldsz[tid];
        if (v != 0.f) atomicAdd(&gz[tid], v);
    }
}

// ---- final: out[g] = sigmoid(gz[g] + fcb) ----
__global__ void sig_k(const float* __restrict__ gz, const float* __restrict__ fcb,
                      float* __restrict__ out) {
    int g = threadIdx.x;
    out[g] = 1.0f / (1.0f + expf(-(gz[g] + fcb[0])));
}

extern "C" void kernel_launch(void* const* d_in, const int* in_sizes, int n_in,
                              void* d_out, int out_size, void* d_ws, size_t ws_size,
                              hipStream_t stream) {
    const float* x    = (const float*)d_in[0];
    const int*   ei   = (const int*)d_in[1];
    const int*   batch= (const int*)d_in[2];
    const float* W1   = (const float*)d_in[3];
    const float* b1   = (const float*)d_in[4];
    const float* W2   = (const float*)d_in[5];
    const float* b2   = (const float*)d_in[6];
    const float* fcw  = (const float*)d_in[7];
    const float* fcb  = (const float*)d_in[8];
    float* out = (float*)d_out;

    float* ws = (float*)d_ws;
    int*    binCur   = (int*)(ws + OFF_BINCUR);
    float*  gz       = ws + OFF_GZ;
    int*    bucketBase = (int*)(ws + OFF_BBASE);
    float*  dis      = ws + OFF_DIS;
    int2*   rowRange = (int2*)(ws + OFF_ROWR);
    int*    col      = (int*)(ws + OFF_COL);
    int*    binned   = (int*)(ws + OFF_BINNED);
    __half* hinH     = (__half*)(ws + OFF_HINH);    // aliases binned (dead after sort_k)
    __half* hinH2    = (__half*)(ws + OFF_HINH2);   // aliases binned tail

    const int B = 256;
    int gN   = (N_NODES + B - 1) / B;            // 391
    int gNP  = (N_NODES * 8 + B - 1) / B;        // 3125 (exact)
    int gBin = (N_EDGES + EPB - 1) / EPB;        // 782

    zero_k<<<1, 576, 0, stream>>>(binCur);       // binCur[512] + gz[64]
    bin_k<<<gBin, 512, 0, stream>>>(ei, binCur, binned);
    scanB_k<<<1, 512, 0, stream>>>(binCur, bucketBase);
    sort_k<<<NB, 512, 0, stream>>>(binCur, bucketBase, binned, dis, rowRange, col);

    transform1_k<<<gN, B, 0, stream>>>(x, W1, dis, hinH);
    prop1_k<<<gNP, B, 0, stream>>>(hinH, dis, rowRange, col, b1, W2, hinH2);
    prop2_k<<<gNP, B, 0, stream>>>(hinH2, dis, rowRange, col, b2, batch, fcw, gz);
    sig_k<<<1, NGRAPH, 0, stream>>>(gz, fcb, out);
}